// Round 2
// baseline (375.033 us; speedup 1.0000x reference)
//
#include <hip/hip_runtime.h>

// FastAttention (Performer linear attention), MI355X gfx950.
// B=4 L=4096 H=16 D=E=64 M=256, all fp32 in/out. bf16 MFMA internally.
//
// R2: counted-vmcnt pipeline (T3/T4). Raw s_barrier + lgkmcnt(0) only -- global
// prefetch loads stay in flight ACROSS barriers (no vmcnt(0) drain per iter).
// Double-buffered k/v/q staging tiles -> k1 has 1 barrier/iter, k3 has 2.
// Atomics removed: k1 writes per-chunk partials, k2 reduces 8->1 (fallback to
// atomic path if ws too small). Lane-consecutive 16B/lane global loads.

#define LL 4096
#define HH 16
#define DD 64
#define EE 64
#define MM 256
#define SCALE 0.35355339059327378f  // 64^-0.25

typedef __attribute__((ext_vector_type(8))) __bf16 bf8v;
typedef __attribute__((ext_vector_type(4))) __bf16 bf4v;
typedef __attribute__((ext_vector_type(4))) float f4v;

__device__ __forceinline__ __bf16 f2bf(float f) {
  // round-to-nearest-even fp32 -> bf16 (inputs are normal floats)
  union { float f; unsigned u; } x; x.f = f;
  unsigned r = (x.u + 0x7FFFu + ((x.u >> 16) & 1u)) >> 16;
  union { unsigned short s; __bf16 b; } y; y.s = (unsigned short)r;
  return y.b;
}

// Barrier with LDS-visibility only: does NOT drain vmcnt, so prefetched global
// loads stay in flight across it. Trailing empty asm = compiler fence so later
// LDS reads can't hoist above the barrier.
__device__ __forceinline__ void barrier_lgkm() {
  asm volatile("s_waitcnt lgkmcnt(0)" ::: "memory");
  __builtin_amdgcn_s_barrier();
  asm volatile("" ::: "memory");
}

#define MFMA16(a, b, c) __builtin_amdgcn_mfma_f32_16x16x32_bf16(a, b, c, 0, 0, 0)

// ws layout (floats), partial path:
//   [ pkv: 8 chunk * 64 bh * 64 e * 256 m ][ pks: 8 * 64 * 256 ]
//   [ kv : 64 bh * 64 e * 256 m ][ ks: 64 * 256 ]
#define PKV_ELEMS (8ull * 64 * 64 * 256)  // 8,388,608
#define PKS_ELEMS (8ull * 64 * 256)       //   131,072
#define KV_ELEMS (64ull * 64 * 256)       // 1,048,576
#define KS_ELEMS (64ull * 256)            //    16,384
#define WS_PART_BYTES ((PKV_ELEMS + PKS_ELEMS + KV_ELEMS + KS_ELEMS) * 4)
#define WS_ATOMIC_BYTES ((KV_ELEMS + KS_ELEMS) * 4)

// ---------------------------------------------------------------------------
// Kernel 1: build KV and Ksum (per-chunk partials, or atomic fallback).
// grid (8 chunks, 64 bh), 512 threads (8 waves). 8 iters of 64 rows.
// Per wave: m-band [32*w, 32*w+32).
// Pipeline: dbuf kt/vt, depth-2 register prefetch, ONE raw barrier per iter.
// ---------------------------------------------------------------------------
__global__ __launch_bounds__(512, 4)
void k1_kv(const float* __restrict__ kin, const float* __restrict__ vin,
           const float* __restrict__ pin,
           float* __restrict__ pkv, float* __restrict__ pks,
           float* __restrict__ kv, float* __restrict__ ks, int partials) {
  __shared__ __bf16 kt[2][64 * 72];   // k tile [l][d], stride 72 (b128-aligned)
  __shared__ __bf16 vt[2][64 * 68];   // v tile [l][e], stride 68 (b64 writes, ~2-way reads)
  __shared__ __bf16 kft[256 * 72];    // phi(k)^T [m][l]; per-wave band, same-wave RAW only

  const int tid = threadIdx.x;
  const int w = tid >> 6;      // wave 0..7, m-band 32*w
  const int lane = tid & 63;
  const int qd = lane >> 4;
  const int nn = lane & 15;
  const int bh = blockIdx.y;
  const int b = bh >> 4, h = bh & 15;
  const int l0 = blockIdx.x * 512;

  const size_t bhbase = (size_t)b * LL * HH * DD + (size_t)h * DD;
  // lane-consecutive staging map: 16 threads cover one 256B row; each thread
  // owns rows r0 and r0+32 of the 64-row tile.
  const int r0 = tid >> 4;          // 0..31
  const int c0 = (tid & 15) * 4;    // float col 0..60

  const float* gk = kin + bhbase + (size_t)(l0 + r0) * (HH * DD) + c0;
  const float* gv = vin + bhbase + (size_t)(l0 + r0) * (HH * DD) + c0;
  const size_t RSTEP = (size_t)32 * HH * DD;  // +32 rows
  const size_t TSTEP = (size_t)64 * HH * DD;  // +64 rows (next tile)

  // ---- issue tiles 0,1 (depth-2 prefetch) ----
  f4v kr[2][2], vr[2][2];
  kr[0][0] = *(const f4v*)gk;          kr[0][1] = *(const f4v*)(gk + RSTEP);
  vr[0][0] = *(const f4v*)gv;          vr[0][1] = *(const f4v*)(gv + RSTEP);
  gk += TSTEP; gv += TSTEP;
  kr[1][0] = *(const f4v*)gk;          kr[1][1] = *(const f4v*)(gk + RSTEP);
  vr[1][0] = *(const f4v*)gv;          vr[1][1] = *(const f4v*)(gv + RSTEP);
  gk += TSTEP; gv += TSTEP;

  // P fragments (B-operand of GEMM1): rows m = 32*w + mt*16 + nn, k d = c*32+qd*8+j.
  bf8v pf[2][2];
#pragma unroll
  for (int mt = 0; mt < 2; ++mt) {
    const float* pr = pin + (size_t)(32 * w + mt * 16 + nn) * DD;
#pragma unroll
    for (int c = 0; c < 2; ++c) {
      bf8v t;
#pragma unroll
      for (int j = 0; j < 8; ++j) t[j] = f2bf(pr[c * 32 + qd * 8 + j] * SCALE);
      pf[mt][c] = t;
    }
  }

  f4v acc[2][4];  // [mt][et]: C rows m = 32w+mt*16+4qd+r, cols e = et*16+nn
#pragma unroll
  for (int i = 0; i < 2; ++i)
#pragma unroll
    for (int j = 0; j < 4; ++j) acc[i][j] = (f4v){0.f, 0.f, 0.f, 0.f};
  float ksum[2] = {0.f, 0.f};

  auto stage = [&](int buf, const f4v* kk, const f4v* vv) {
    __bf16* ktb = &kt[buf][0];
    __bf16* vtb = &vt[buf][0];
#pragma unroll
    for (int rr = 0; rr < 2; ++rr) {
      bf4v a, c;
#pragma unroll
      for (int j = 0; j < 4; ++j) { a[j] = f2bf(kk[rr][j]); c[j] = f2bf(vv[rr][j]); }
      *(bf4v*)&ktb[(r0 + 32 * rr) * 72 + c0] = a;
      *(bf4v*)&vtb[(r0 + 32 * rr) * 68 + c0] = c;
    }
  };

  auto gemm12 = [&](int buf) {
    const __bf16* ktb = &kt[buf][0];
    const __bf16* vtb = &vt[buf][0];
    // GEMM1: C[l][m] = kt . P^T ; phi ; ksum ; write kft[m][l] (own band, b64)
#pragma unroll
    for (int lt = 0; lt < 4; ++lt) {
      bf8v a0 = *(const bf8v*)&ktb[(lt * 16 + nn) * 72 + qd * 8];
      bf8v a1 = *(const bf8v*)&ktb[(lt * 16 + nn) * 72 + 32 + qd * 8];
#pragma unroll
      for (int mt = 0; mt < 2; ++mt) {
        f4v cc = (f4v){0.f, 0.f, 0.f, 0.f};
        cc = MFMA16(a0, pf[mt][0], cc);
        cc = MFMA16(a1, pf[mt][1], cc);
        // lane holds rows l = lt*16+4qd+r, col m = 32w+mt*16+nn
        bf4v pk4;
#pragma unroll
        for (int r = 0; r < 4; ++r) {
          float ph = fmaxf(cc[r], 0.f) + 1e-3f;
          ksum[mt] += ph;
          pk4[r] = f2bf(ph);
        }
        *(bf4v*)&kft[(32 * w + mt * 16 + nn) * 72 + lt * 16 + qd * 4] = pk4;
      }
    }
    // GEMM2: acc[m][e] += kft(own band) . v  (same-wave kft RAW via lgkmcnt)
#pragma unroll
    for (int c = 0; c < 2; ++c) {
      bf8v af0 = *(const bf8v*)&kft[(32 * w + nn) * 72 + c * 32 + qd * 8];
      bf8v af1 = *(const bf8v*)&kft[(32 * w + 16 + nn) * 72 + c * 32 + qd * 8];
#pragma unroll
      for (int et = 0; et < 4; ++et) {
        bf8v bv;  // B[k=l][n=e]: column of vt (8 scalar reads, ~2-way)
#pragma unroll
        for (int j = 0; j < 8; ++j) bv[j] = vtb[(c * 32 + qd * 8 + j) * 68 + et * 16 + nn];
        acc[0][et] = MFMA16(af0, bv, acc[0][et]);
        acc[1][et] = MFMA16(af1, bv, acc[1][et]);
      }
    }
  };

  // prologue: stage tile 0, make visible
  stage(0, kr[0], vr[0]);
  barrier_lgkm();

#pragma unroll
  for (int t = 0; t < 8; ++t) {
    const int cur = t & 1;
    // issue loads for tile t+2 into the reg set freed at end of last iter
    if (t + 2 < 8) {
      kr[cur][0] = *(const f4v*)gk;      kr[cur][1] = *(const f4v*)(gk + RSTEP);
      vr[cur][0] = *(const f4v*)gv;      vr[cur][1] = *(const f4v*)(gv + RSTEP);
      gk += TSTEP; gv += TSTEP;
    }
    gemm12(cur);
    if (t + 1 < 8) {
      stage(cur ^ 1, kr[cur ^ 1], vr[cur ^ 1]);  // compiler waits vmcnt(4) here
      barrier_lgkm();
    }
  }

  // ---- epilogue ----
  if (partials) {
    // plain coalesced partial stores: [chunk][bh][e][m]; full 64B lines per instr
    float* dst = pkv + (size_t)(blockIdx.x * 64 + bh) * (64 * 256);
#pragma unroll
    for (int mt = 0; mt < 2; ++mt)
#pragma unroll
      for (int et = 0; et < 4; ++et) {
        int m0 = 32 * w + mt * 16 + 4 * qd;
        int e = et * 16 + nn;
        *(f4v*)&dst[e * 256 + m0] = acc[mt][et];
      }
#pragma unroll
    for (int mt = 0; mt < 2; ++mt) {
      float s = ksum[mt];
      s += __shfl_xor(s, 16, 64);
      s += __shfl_xor(s, 32, 64);
      if (lane < 16)
        pks[(size_t)(blockIdx.x * 64 + bh) * 256 + 32 * w + mt * 16 + lane] = s;
    }
  } else {
    float* kvb = kv + (size_t)bh * (64 * 256);
#pragma unroll
    for (int mt = 0; mt < 2; ++mt)
#pragma unroll
      for (int et = 0; et < 4; ++et)
#pragma unroll
        for (int r = 0; r < 4; ++r) {
          int m = 32 * w + mt * 16 + 4 * qd + r;
          int e = et * 16 + nn;
          atomicAdd(&kvb[e * 256 + m], acc[mt][et][r]);
        }
#pragma unroll
    for (int mt = 0; mt < 2; ++mt) {
      float s = ksum[mt];
      s += __shfl_xor(s, 16, 64);
      s += __shfl_xor(s, 32, 64);
      if (lane < 16) atomicAdd(&ks[bh * 256 + 32 * w + mt * 16 + lane], s);
    }
  }
}

// ---------------------------------------------------------------------------
// Kernel 2: reduce 8 chunk-partials -> final KV / Ksum. Pure streaming.
// grid 1040 x 256: 262144 f4v of KV + 4096 f4v of Ksum.
// ---------------------------------------------------------------------------
__global__ __launch_bounds__(256)
void k2_red(const float* __restrict__ pkv, const float* __restrict__ pks,
            float* __restrict__ kv, float* __restrict__ ks) {
  const int idx = blockIdx.x * 256 + threadIdx.x;
  if (idx < 262144) {
    f4v s = (f4v){0.f, 0.f, 0.f, 0.f};
#pragma unroll
    for (int x = 0; x < 8; ++x) s += ((const f4v*)pkv)[(size_t)x * 262144 + idx];
    ((f4v*)kv)[idx] = s;
  } else {
    const int j = idx - 262144;  // < 4096
    f4v s = (f4v){0.f, 0.f, 0.f, 0.f};
#pragma unroll
    for (int x = 0; x < 8; ++x) s += ((const f4v*)pks)[x * 4096 + j];
    ((f4v*)ks)[j] = s;
  }
}

// ---------------------------------------------------------------------------
// Kernel 3: out = (phi(q) @ KV) / (phi(q) . (Ksum+1e-6)).
// grid (8, 64), 512 threads (8 waves = wm 0..3 x wl 0..1), 8 iters of 64 rows.
// dbuf qt, depth-2 prefetch, 2 raw barriers/iter (qt-visible, qf/denp-visible).
// ---------------------------------------------------------------------------
__global__ __launch_bounds__(512, 4)
void k3_out(const float* __restrict__ qin, const float* __restrict__ pin,
            const float* __restrict__ kv, const float* __restrict__ ksm,
            float* __restrict__ out) {
  __shared__ __bf16 qt[2][64 * 72];  // q tile [l][d]
  __shared__ __bf16 qf[64 * 264];    // phi(q) [l][m], stride 264
  __shared__ float denp[256];        // den partials [wm][l]
  __shared__ float ksume[256];       // Ksum + 1e-6

  const int tid = threadIdx.x;
  const int w = tid >> 6;
  const int wm = w & 3;
  const int wl = w >> 2;
  const int lane = tid & 63;
  const int qd = lane >> 4;
  const int nn = lane & 15;
  const int bh = blockIdx.y;
  const int b = bh >> 4, h = bh & 15;
  const int l0 = blockIdx.x * 512;
  const int lt0 = 2 * wl;

  const size_t bhbase = (size_t)b * LL * HH * DD + (size_t)h * DD;
  const int r0 = tid >> 4;
  const int c0 = (tid & 15) * 4;

  const float* gq = qin + bhbase + (size_t)(l0 + r0) * (HH * DD) + c0;
  const size_t RSTEP = (size_t)32 * HH * DD;
  const size_t TSTEP = (size_t)64 * HH * DD;

  // ---- issue q tiles 0,1 ----
  f4v qr[2][2];
  qr[0][0] = *(const f4v*)gq;  qr[0][1] = *(const f4v*)(gq + RSTEP);
  gq += TSTEP;
  qr[1][0] = *(const f4v*)gq;  qr[1][1] = *(const f4v*)(gq + RSTEP);
  gq += TSTEP;

  // P fragments (A-operand of GEMM3': rows m = 64*wm + mt*16 + nn).
  bf8v pf[4][2];
#pragma unroll
  for (int mt = 0; mt < 4; ++mt) {
    const float* pr = pin + (size_t)(64 * wm + mt * 16 + nn) * DD;
#pragma unroll
    for (int c = 0; c < 2; ++c) {
      bf8v t;
#pragma unroll
      for (int j = 0; j < 8; ++j) t[j] = f2bf(pr[c * 32 + qd * 8 + j] * SCALE);
      pf[mt][c] = t;
    }
  }

  // KV fragments: B[k=m][n=e], e = 16*wm + nn, m = c*32 + qd*8 + j (dup over wl).
  const float* kvb = kv + (size_t)bh * (64 * 256);
  bf8v kvf[8];
#pragma unroll
  for (int c = 0; c < 8; ++c) {
    const float* src = kvb + (size_t)(16 * wm + nn) * 256 + c * 32 + qd * 8;
    bf8v t;
#pragma unroll
    for (int j = 0; j < 8; ++j) t[j] = f2bf(src[j]);
    kvf[c] = t;
  }

  if (tid < 256) ksume[tid] = ksm[bh * 256 + tid] + 1e-6f;  // Z_EPS

  auto stage = [&](int buf, const f4v* qq) {
    __bf16* qtb = &qt[buf][0];
#pragma unroll
    for (int rr = 0; rr < 2; ++rr) {
      bf4v a;
#pragma unroll
      for (int j = 0; j < 4; ++j) a[j] = f2bf(qq[rr][j]);
      *(bf4v*)&qtb[(r0 + 32 * rr) * 72 + c0] = a;
    }
  };

  stage(0, qr[0]);
  barrier_lgkm();  // qt0 + ksume visible

#pragma unroll
  for (int t = 0; t < 8; ++t) {
    const int cur = t & 1;
    if (t + 2 < 8) {
      qr[cur][0] = *(const f4v*)gq;  qr[cur][1] = *(const f4v*)(gq + RSTEP);
      gq += TSTEP;
    }

    // ---- GEMM3': C[m][l] = P . q^T ; phi ; den partial ; write qf[l][m] ----
    {
      const __bf16* qtb = &qt[cur][0];
#pragma unroll
      for (int li = 0; li < 2; ++li) {
        const int lt = lt0 + li;
        bf8v b0 = *(const bf8v*)&qtb[(lt * 16 + nn) * 72 + qd * 8];
        bf8v b1 = *(const bf8v*)&qtb[(lt * 16 + nn) * 72 + 32 + qd * 8];
        float dpart = 0.f;  // lane's col l = lt*16+nn
#pragma unroll
        for (int mt = 0; mt < 4; ++mt) {
          f4v cc = (f4v){0.f, 0.f, 0.f, 0.f};
          cc = MFMA16(pf[mt][0], b0, cc);
          cc = MFMA16(pf[mt][1], b1, cc);
          // lane holds rows m = 64wm+mt*16+4qd+r, col l = lt*16+nn
          bf4v pk4;
#pragma unroll
          for (int r = 0; r < 4; ++r) {
            float ph = fmaxf(cc[r], 0.f) + 1e-3f;
            dpart += ph * ksume[64 * wm + mt * 16 + 4 * qd + r];
            pk4[r] = f2bf(ph);
          }
          *(bf4v*)&qf[(lt * 16 + nn) * 264 + 64 * wm + mt * 16 + 4 * qd] = pk4;
        }
        dpart += __shfl_xor(dpart, 16, 64);
        dpart += __shfl_xor(dpart, 32, 64);
        if (lane < 16) denp[wm * 64 + lt * 16 + lane] = dpart;
      }
    }
    barrier_lgkm();  // qf + denp visible

    // ---- GEMM4: out[l][e] = qf . KV, scale by 1/den, store ----
#pragma unroll
    for (int li = 0; li < 2; ++li) {
      const int lt = lt0 + li;
      f4v co = (f4v){0.f, 0.f, 0.f, 0.f};
#pragma unroll
      for (int c = 0; c < 8; ++c) {
        bf8v af = *(const bf8v*)&qf[(lt * 16 + nn) * 264 + c * 32 + qd * 8];
        co = MFMA16(af, kvf[c], co);
      }
      f4v d0 = *(const f4v*)&denp[0 * 64 + lt * 16 + 4 * qd];
      f4v d1 = *(const f4v*)&denp[1 * 64 + lt * 16 + 4 * qd];
      f4v d2 = *(const f4v*)&denp[2 * 64 + lt * 16 + 4 * qd];
      f4v d3 = *(const f4v*)&denp[3 * 64 + lt * 16 + 4 * qd];
#pragma unroll
      for (int r = 0; r < 4; ++r) {
        int lrel = lt * 16 + 4 * qd + r;
        int labs = l0 + t * 64 + lrel;
        float rden = 1.f / (d0[r] + d1[r] + d2[r] + d3[r]);
        out[((size_t)((size_t)b * LL + labs) * HH + h) * EE + 16 * wm + nn] =
            co[r] * rden;
      }
    }

    if (t + 1 < 8) {
      stage(cur ^ 1, qr[cur ^ 1]);
      barrier_lgkm();  // qt(t+1) visible; also fences qf/denp WAR for next GEMM3'
    }
  }
}

extern "C" void kernel_launch(void* const* d_in, const int* in_sizes, int n_in,
                              void* d_out, int out_size, void* d_ws, size_t ws_size,
                              hipStream_t stream) {
  (void)in_sizes; (void)n_in; (void)out_size;
  const float* q = (const float*)d_in[0];
  const float* k = (const float*)d_in[1];
  const float* v = (const float*)d_in[2];
  const float* p = (const float*)d_in[3];
  float* ws = (float*)d_ws;
  float* out = (float*)d_out;

  dim3 grid(8, 64), blk(512);
  if (ws_size >= WS_PART_BYTES) {
    float* pkv = ws;
    float* pks = ws + PKV_ELEMS;
    float* kvp = ws + PKV_ELEMS + PKS_ELEMS;
    float* ksp = kvp + KV_ELEMS;
    k1_kv<<<grid, blk, 0, stream>>>(k, v, p, pkv, pks, nullptr, nullptr, 1);
    k2_red<<<dim3(1040), dim3(256), 0, stream>>>(pkv, pks, kvp, ksp);
    k3_out<<<grid, blk, 0, stream>>>(q, p, kvp, ksp, out);
  } else if (ws_size >= WS_ATOMIC_BYTES) {
    float* kvp = ws;
    float* ksp = ws + KV_ELEMS;
    hipMemsetAsync(d_ws, 0, WS_ATOMIC_BYTES, stream);
    k1_kv<<<grid, blk, 0, stream>>>(k, v, p, nullptr, nullptr, kvp, ksp, 0);
    k3_out<<<grid, blk, 0, stream>>>(q, p, kvp, ksp, out);
  }
}